// Round 13
// baseline (88.115 us; speedup 1.0000x reference)
//
#include <hip/hip_runtime.h>

#define B_ 2048
#define T_ 500
#define BT (B_ * T_)

// ---------------------------------------------------------------------------
// Masked Izhikevich Euler step — association order matches the reference
// exactly (DT=0.25, all a=0.02 -> DT*a = 0.005f). Invalid lanes hold state.
// ---------------------------------------------------------------------------
__device__ __forceinline__ float izh_m(float& v, float& u, float I,
                                       float b, float c, float d, bool valid) {
    float t  = 0.04f * v * v + 5.0f * v + 140.0f - u + I;
    float v_ = v + 0.25f * t;
    float u_ = u + 0.005f * (b * v - u);
    float z  = (v_ >= 30.0f) ? 1.0f : 0.0f;
    float vn = (v_ >= 30.0f) ? c : v_;
    float un = u_ + z * d;
    if (!valid) { z = 0.f; vn = v; un = u; }
    v = vn; u = un;
    return z;
}

// DPP helpers (full-rate VALU cross-lane).
__device__ __forceinline__ float dpp_shr1(float x) {
    return __int_as_float(__builtin_amdgcn_update_dpp(
        0, __float_as_int(x), 0x111, 0xf, 0xf, true));
}
__device__ __forceinline__ float dpp_shr2(float x) {
    return __int_as_float(__builtin_amdgcn_update_dpp(
        0, __float_as_int(x), 0x112, 0xf, 0xf, true));
}
// quad_perm [1,0,3,2] = lane^1 within quads
__device__ __forceinline__ float dpp_qx1(float x) {
    return __int_as_float(__builtin_amdgcn_update_dpp(
        0, __float_as_int(x), 0xB1, 0xf, 0xf, true));
}
// quad_perm [2,3,0,1] = lane^2 within quads
__device__ __forceinline__ float dpp_qx2(float x) {
    return __int_as_float(__builtin_amdgcn_update_dpp(
        0, __float_as_int(x), 0x4E, 0xf, 0xf, true));
}

// LDS-only workgroup barrier (lgkmcnt, never vmcnt) — prefetch loads stay in
// flight across it; DUMP's global stores drain at kernel end.
#define BAR() do {                                                             \
    asm volatile("s_waitcnt lgkmcnt(0)" ::: "memory");                         \
    __builtin_amdgcn_s_barrier();                                              \
    __builtin_amdgcn_sched_barrier(0);                                         \
} while (0)

// ---------------------------------------------------------------------------
// FUSED producer-consumer kernel, v5. 512 blocks x 128 threads (2 waves):
//   wave 0 = scanner: gap-3 systolic pipeline (unchanged from v4).
//   wave 1 = loader: 16 FULLY-CONTIGUOUS 1KB loads per period (16 whole
//            64B-lines each, ~16 merged TA requests vs 32 partials before),
//            2-period-deep reg ping-pong. Reduction: 16 lanes per (row,t)
//            atom, leaf (x+y)+(z+w), xor1/xor2 via DPP quad_perm, xor4/xor8
//            via shfl_xor — association-identical to the reference rowsum.
// ---------------------------------------------------------------------------
__global__ __launch_bounds__(128) void fused_scan5_kernel(
        const float* __restrict__ in, const float* __restrict__ w24,
        float* __restrict__ out) {
    __shared__ float S_lds[128];       // [2 bufs][4 rows][16 t]
    __shared__ float ring[32 * 56];    // [32 slots][4 chains * 14 floats]

    const int tid   = threadIdx.x;
    const int wid   = tid >> 6;        // 0 = scanner, 1 = loader
    const int lane  = tid & 63;
    const int bbase = blockIdx.x << 2; // 4 batch rows per block

    // ---------------- scanner per-lane config ----------------
    const int c    = lane >> 4;        // chain 0..3
    const int slot = lane & 15;
    const int chl  = slot >> 3;        // 0 = channel 1, 1 = channel 2
    const int role = slot & 7;         // 0..4 active, 5..7 idle

    const float a0   = chl ? w24[12] : w24[0];
    const float W1v  = chl ? w24[13] : w24[1];
    const float W4v  = chl ? w24[16] : w24[4];
    const float W5x  = chl ? w24[17] : w24[5];
    const float W6v  = chl ? w24[18] : w24[6];
    const float W8v  = chl ? w24[20] : w24[8];
    const float W11v = chl ? w24[23] : w24[11];
    const float W2 = w24[2], W3 = w24[3], W9 = w24[9], W10 = w24[10];

    float pb, pcc, pd, v, u, wA, wB, wC, wD;
    float fL = 0.f, fE = 0.f, fITM = 0.f;
    float sel1 = 0.f, sel2 = 0.f;      // DPP source select (exact {0,1})
    int offs;
    if (role == 0) {        // LLBN: I = w2*(zp*w1) + w3*z2(self prev)
        pb=0.20f; pcc=-65.f; pd=6.f;   v=-70.f; u=-14.f;
        wA=W2;  wB=W1v;  wC=0.f; wD=W3;  offs=0; fL=1.f;
    } else if (role == 1) { // EBN: I = zp*w4 + z2*w5   (z2 <- slot-1)
        pb=0.25f; pcc=-55.f; pd=0.05f; v=-64.f; u=-16.f;
        wA=1.f; wB=W4v;  wC=W5x; wD=0.f; offs=3; fE=1.f; sel1=1.f;
    } else if (role == 2) { // IFN: I = z3*w6           (z3 <- slot-1)
        pb=0.25f; pcc=-65.f; pd=6.f;   v=-64.f; u=-16.f;
        wA=1.f; wB=W6v;  wC=0.f; wD=0.f; offs=6; fITM=1.f; sel1=1.f;
    } else if (role == 3) { // TN: I = w9*(z3*w8) + w10*z5(self prev) (z3 <- slot-2)
        pb=0.20f; pcc=-50.f; pd=2.f;   v=-70.f; u=-14.f;
        wA=W9;  wB=W8v;  wC=0.f; wD=W10; offs=6; fITM=1.f; sel2=1.f;
    } else if (role == 4) { // MN: I = z5*w11           (z5 <- slot-1)
        pb=0.25f; pcc=-65.f; pd=6.f;   v=-64.f; u=-16.f;
        wA=1.f; wB=W11v; wC=0.f; wD=0.f; offs=9; fITM=1.f; sel1=1.f;
    } else {                // idle
        pb=0.25f; pcc=-65.f; pd=6.f;   v=-64.f; u=-16.f;
        wA=0.f; wB=0.f;  wC=0.f; wD=0.f; offs=9;
    }
    const bool wr = (chl == 0 && role <= 4) || (chl == 1 && role == 4);
    const int  p  = (chl == 0) ? role : 5;
    const int ringoff = c * 14 + 2 * p;

    float z_last = 0.f, in_p1 = 0.f, in_p2 = 0.f;
    float zp1 = 0.f, zp2 = 0.f, zp3 = 0.f;

    const float* inb = in + (size_t)bbase * T_ * 64;
    // loader ping-pong register buffers (static indexing via full unroll)
    float4 Ca[16], Cb[16];

// 16 contiguous 1KB wave-loads: instr ii covers row r = ii>>2, t-quad tq =
// ii&3 (t = t0+4*tq .. +3). Tail clamp is wave-uniform (block base only).
#define ISSUE(KK, CB) {                                                        \
    const int t0i = 16 * (KK);                                                 \
    _Pragma("unroll")                                                          \
    for (int ii = 0; ii < 16; ++ii) {                                          \
        const int r = ii >> 2, tq4 = (ii & 3) * 4;                             \
        const int tqe = (t0i + tq4 + 3 <= 499) ? tq4 : 0;                      \
        const float* ap = inb + ((size_t)r * T_ + t0i + tqe) * 64 + lane * 4;  \
        CB[ii] = *(const float4*)ap;                                           \
    }                                                                          \
}

// Exact original rowsum tree per 16-lane atom: leaf (x+y)+(z+w);
// xor1, xor2 (DPP quad_perm), xor4, xor8 (shfl_xor). Lane (l&15)==0 writes.
#define REDUCE(KK, CB) {                                                       \
    float* sw = S_lds + ((KK) & 1) * 64;                                       \
    const int t0r = 16 * (KK);                                                 \
    _Pragma("unroll")                                                          \
    for (int ii = 0; ii < 16; ++ii) {                                          \
        float4 vv = CB[ii];                                                    \
        float s = (vv.x + vv.y) + (vv.z + vv.w);                               \
        s += dpp_qx1(s);                                                       \
        s += dpp_qx2(s);                                                       \
        s += __shfl_xor(s, 4);                                                 \
        s += __shfl_xor(s, 8);                                                 \
        const int r = ii >> 2, tt = (ii & 3) * 4 + (lane >> 4);                \
        if ((lane & 15) == 0) sw[r * 16 + tt] = (t0r + tt <= 499) ? s : 0.f;   \
    }                                                                          \
}

#define SYS_ITER(SV, VEXPR, I_) {                                              \
    float in0 = in_p2;                                                         \
    in_p2 = in_p1;                                                             \
    {                                                                          \
        float s1_ = dpp_shr1(z_last);                                          \
        float s2_ = dpp_shr2(z_last);                                          \
        in_p1 = sel1 * s1_ + sel2 * s2_;                                       \
    }                                                                          \
    float zpc = (SV) * a0;                                                     \
    float X = (fL * zpc + fE * zp3) + fITM * in0;                              \
    float Isyn = wA * (X * wB) + wC * in0 + wD * z_last;                       \
    float znew = izh_m(v, u, Isyn, pb, pcc, pd, (VEXPR));                      \
    if (wr) *(float2*)(ringp + (I_) * 56) = make_float2(znew, v);              \
    zp3 = zp2; zp2 = zp1; zp1 = zpc;                                           \
    z_last = znew;                                                             \
}

#define GROUP16(VF)                                                            \
    SYS_ITER(g0.x, VF(0),  0)  SYS_ITER(g0.y, VF(1),  1)                       \
    SYS_ITER(g0.z, VF(2),  2)  SYS_ITER(g0.w, VF(3),  3)                       \
    SYS_ITER(g1.x, VF(4),  4)  SYS_ITER(g1.y, VF(5),  5)                       \
    SYS_ITER(g1.z, VF(6),  6)  SYS_ITER(g1.w, VF(7),  7)                       \
    SYS_ITER(g2.x, VF(8),  8)  SYS_ITER(g2.y, VF(9),  9)                       \
    SYS_ITER(g2.z, VF(10), 10) SYS_ITER(g2.w, VF(11), 11)                      \
    SYS_ITER(g3.x, VF(12), 12) SYS_ITER(g3.y, VF(13), 13)                      \
    SYS_ITER(g3.z, VF(14), 14) SYS_ITER(g3.w, VF(15), 15)

#define VF_PRO(i)  ((i) >= offs)
#define VF_ONE(i)  true
#define VF_EPI(i)  ((i) <= 3 + offs)

#define DUMP(K) {                                                              \
    const int td = lane & 15;                                                  \
    const int cc = lane >> 4;                                                  \
    const int t  = 16 * (K) - 9 + td;                                          \
    if (0 <= t && t <= 499) {                                                  \
        const float* rb = ring + cc * 14;                                      \
        float2 a2 = *(const float2*)&rb[((t)     & 31) * 56 + 0];              \
        float2 b2 = *(const float2*)&rb[((t + 3) & 31) * 56 + 2];              \
        float2 c1 = *(const float2*)&rb[((t + 6) & 31) * 56 + 4];              \
        float2 c2 = *(const float2*)&rb[((t + 6) & 31) * 56 + 6];              \
        float2 e1 = *(const float2*)&rb[((t + 9) & 31) * 56 + 8];              \
        float2 e2 = *(const float2*)&rb[((t + 9) & 31) * 56 + 10];             \
        const size_t g = (size_t)(bbase + cc) * T_ + t;                        \
        out[g]          = e1.x;   /* o_spikes  = z6  */                        \
        out[BT + g]     = e1.y;   /* v         = vM  */                        \
        out[2 * BT + g] = e2.x;   /* o_spikes2 = z62 */                        \
        out[3 * BT + g] = e2.y;   /* v2        = vM2 */                        \
        ((float4*)out)[BT + g]     = make_float4(a2.x, b2.x, c1.x, c2.x);      \
        ((float4*)out)[2 * BT + g] = make_float4(a2.y, b2.y, c1.y, c2.y);      \
    }                                                                          \
}

#define SCANP(K, VFSEL) {                                                      \
    const float4* sp = (const float4*)(S_lds + ((K) & 1) * 64 + c * 16);       \
    float4 g0 = sp[0], g1 = sp[1], g2 = sp[2], g3 = sp[3];                     \
    float* ringp = ring + ((K) & 1) * 896 + ringoff;                           \
    GROUP16(VFSEL)                                                             \
    DUMP(K)                                                                    \
}

    // ---------------- prologue ----------------
    if (wid == 1) {
        ISSUE(0, Ca)
        REDUCE(0, Ca)          // counted vmcnt on consume (compiler-emitted)
        ISSUE(1, Cb)
    }
    BAR();                     // S_lds buf0 ready; ISSUE(1) stays in flight

    // ---------------- main: periods 0..31 (unrolled x2 for reg ping-pong) ---
    for (int k = 0; k < 32; k += 2) {
        if (wid == 0) {
            if (k == 0) { SCANP(k, VF_PRO) } else { SCANP(k, VF_ONE) }
        } else {
            if (k + 2 < 32) { ISSUE(k + 2, Ca) }
            if (k + 1 < 32) { REDUCE(k + 1, Cb) }
        }
        BAR();
        if (wid == 0) {
            if (k + 1 == 31) { SCANP(k + 1, VF_EPI) } else { SCANP(k + 1, VF_ONE) }
        } else {
            if (k + 3 < 32) { ISSUE(k + 3, Cb) }
            if (k + 2 < 32) { REDUCE(k + 2, Ca) }
        }
        BAR();
    }

#undef ISSUE
#undef REDUCE
#undef SYS_ITER
#undef GROUP16
#undef VF_PRO
#undef VF_ONE
#undef VF_EPI
#undef DUMP
#undef SCANP
}

extern "C" void kernel_launch(void* const* d_in, const int* in_sizes, int n_in,
                              void* d_out, int out_size, void* d_ws, size_t ws_size,
                              hipStream_t stream) {
    const float* in = (const float*)d_in[0];
    const float* w  = (const float*)d_in[1];
    float* out = (float*)d_out;

    // 512 blocks x 128 threads (1 scanner wave + 1 loader wave),
    // 4 batch rows per block; no workspace needed.
    fused_scan5_kernel<<<512, 128, 0, stream>>>(in, w, out);
}

// Round 14
// 72.542 us; speedup vs baseline: 1.2147x; 1.2147x over previous
//
#include <hip/hip_runtime.h>

#define B_ 2048
#define T_ 500
#define BT (B_ * T_)

// ---------------------------------------------------------------------------
// Masked Izhikevich Euler step — association order matches the reference
// exactly (DT=0.25, all a=0.02 -> DT*a = 0.005f). Invalid lanes hold state.
// ---------------------------------------------------------------------------
__device__ __forceinline__ float izh_m(float& v, float& u, float I,
                                       float b, float c, float d, bool valid) {
    float t  = 0.04f * v * v + 5.0f * v + 140.0f - u + I;
    float v_ = v + 0.25f * t;
    float u_ = u + 0.005f * (b * v - u);
    float z  = (v_ >= 30.0f) ? 1.0f : 0.0f;
    float vn = (v_ >= 30.0f) ? c : v_;
    float un = u_ + z * d;
    if (!valid) { z = 0.f; vn = v; un = u; }
    v = vn; u = un;
    return z;
}

// DPP row-shift-right by 1 within each 16-lane row; OOB lanes read 0.
__device__ __forceinline__ float dpp_shr1(float x) {
    return __int_as_float(__builtin_amdgcn_update_dpp(
        0, __float_as_int(x), 0x111, 0xf, 0xf, true));
}

// LDS-only workgroup barrier (lgkmcnt, never vmcnt) — prefetch loads stay in
// flight across it; global stores drain at kernel end.
#define BAR() do {                                                             \
    asm volatile("s_waitcnt lgkmcnt(0)" ::: "memory");                         \
    __builtin_amdgcn_s_barrier();                                              \
    __builtin_amdgcn_sched_barrier(0);                                         \
} while (0)

// ---------------------------------------------------------------------------
// FUSED producer-consumer kernel, v6. 512 blocks x 128 threads (2 waves):
//   wave 0 = scanner ONLY scans: gap-3 systolic pipeline with ALL-DISTANCE-1
//            slot layout per 8-lane half: 0:L 1:E 2:I 3:idle 4:L' 5:E' 6:T 7:M
//            (L',E' = exact duplicate compute on formerly-idle lanes so every
//            transport is one dpp_shr1). Writes raw (z,v) to a 64-deep ring.
//   wave 1 = loader (v4 form: 2-period reg ping-pong, strided loads) + DUMP
//            of period K during period K+1 (64-deep ring makes this race-free:
//            concurrent writes are <=40 iters ahead of dump reads < 64).
// ---------------------------------------------------------------------------
__global__ __launch_bounds__(128) void fused_scan6_kernel(
        const float* __restrict__ in, const float* __restrict__ w24,
        float* __restrict__ out) {
    __shared__ float S_lds[128];       // [2 bufs][4 rows][16 t]
    __shared__ float ring[64 * 56];    // [64 slots][4 chains * 14 floats]

    const int tid   = threadIdx.x;
    const int wid   = tid >> 6;        // 0 = scanner, 1 = loader
    const int lane  = tid & 63;
    const int bbase = blockIdx.x << 2; // 4 batch rows per block

    // ---------------- scanner per-lane config ----------------
    const int c     = lane >> 4;       // chain 0..3
    const int slot  = lane & 15;
    const int chl   = slot >> 3;       // 0 = channel 1, 1 = channel 2
    const int role8 = slot & 7;        // 0:L 1:E 2:I 3:idle 4:L' 5:E' 6:T 7:M

    const float a0   = chl ? w24[12] : w24[0];
    const float W1v  = chl ? w24[13] : w24[1];
    const float W4v  = chl ? w24[16] : w24[4];
    const float W5x  = chl ? w24[17] : w24[5];
    const float W6v  = chl ? w24[18] : w24[6];
    const float W8v  = chl ? w24[20] : w24[8];
    const float W11v = chl ? w24[23] : w24[11];
    const float W2 = w24[2], W3 = w24[3], W9 = w24[9], W10 = w24[10];

    float pb, pcc, pd, v, u, wA, wB, wC, wD;
    float fL = 0.f, fE = 0.f, fITM = 0.f;
    int offs;
    if (role8 == 0 || role8 == 4) {        // L / L': I = w2*(zp*w1) + w3*z2(self)
        pb=0.20f; pcc=-65.f; pd=6.f;   v=-70.f; u=-14.f;
        wA=W2;  wB=W1v;  wC=0.f; wD=W3;  offs=0; fL=1.f;
    } else if (role8 == 1 || role8 == 5) { // E / E': I = zp*w4 + z2*w5 (z2 <- slot-1)
        pb=0.25f; pcc=-55.f; pd=0.05f; v=-64.f; u=-16.f;
        wA=1.f; wB=W4v;  wC=W5x; wD=0.f; offs=3; fE=1.f;
    } else if (role8 == 2) {               // I: Isyn = z3*w6 (z3 <- slot-1 = E)
        pb=0.25f; pcc=-65.f; pd=6.f;   v=-64.f; u=-16.f;
        wA=1.f; wB=W6v;  wC=0.f; wD=0.f; offs=6; fITM=1.f;
    } else if (role8 == 6) {               // T: w9*(z3*w8) + w10*z5(self) (z3 <- slot-1 = E')
        pb=0.20f; pcc=-50.f; pd=2.f;   v=-70.f; u=-14.f;
        wA=W9;  wB=W8v;  wC=0.f; wD=W10; offs=6; fITM=1.f;
    } else if (role8 == 7) {               // M: z5*w11 (z5 <- slot-1 = T)
        pb=0.25f; pcc=-65.f; pd=6.f;   v=-64.f; u=-16.f;
        wA=1.f; wB=W11v; wC=0.f; wD=0.f; offs=9; fITM=1.f;
    } else {                               // slot 3: idle
        pb=0.25f; pcc=-65.f; pd=6.f;   v=-64.f; u=-16.f;
        wA=0.f; wB=0.f;  wC=0.f; wD=0.f; offs=9;
    }
    // ring pairs: p0=(z2,vL)@slot0, p1=(z3,vE)@slot1, p2=(z4,vI)@slot2,
    // p3=(z5,vT)@slot6, p4=(z6,vM)@slot7 (ch1); p5=(z62,vM2)@slot15 (ch2).
    const bool wr = (chl == 0 && (role8 <= 2 || role8 == 6 || role8 == 7))
                 || (chl == 1 && role8 == 7);
    int p = 0;
    if (role8 == 1) p = 1;
    else if (role8 == 2) p = 2;
    else if (role8 == 6) p = 3;
    else if (role8 == 7) p = chl ? 5 : 4;
    const int ringoff = c * 14 + 2 * p;

    float z_last = 0.f, in_p1 = 0.f, in_p2 = 0.f;
    float zp1 = 0.f, zp2 = 0.f, zp3 = 0.f;

    const float* inb = in + (size_t)bbase * T_ * 64;
    // loader ping-pong register buffers (static indexing via full unroll)
    float4 Ae[8], Ao[8], Be[8], Bo[8];

#define ISSUE(KK, BE, BO) {                                                    \
    const int t0i = 16 * (KK);                                                 \
    _Pragma("unroll")                                                          \
    for (int pp = 0; pp < 8; ++pp) {                                           \
        const int rt = pp * 8 + (lane >> 3);                                   \
        const int row = rt >> 4, tt = rt & 15;                                 \
        const int tcl = (t0i + tt <= 499) ? tt : 0;                            \
        const float* ap = inb + ((size_t)row * T_ + t0i + tcl) * 64            \
                              + (lane & 7) * 8;                                \
        BE[pp] = *(const float4*)ap;                                           \
        BO[pp] = *(const float4*)(ap + 4);                                     \
    }                                                                          \
}

#define REDUCE(KK, BE, BO) {                                                   \
    float* sw = S_lds + ((KK) & 1) * 64;                                       \
    const int t0r = 16 * (KK);                                                 \
    _Pragma("unroll")                                                          \
    for (int pp = 0; pp < 8; ++pp) {                                           \
        float4 e = BE[pp], o = BO[pp];                                         \
        float s = ((e.x + e.y) + (e.z + e.w)) + ((o.x + o.y) + (o.z + o.w));   \
        s += __shfl_xor(s, 1);                                                 \
        s += __shfl_xor(s, 2);                                                 \
        s += __shfl_xor(s, 4);                                                 \
        const int rt = pp * 8 + (lane >> 3);                                   \
        const int row = rt >> 4, tt = rt & 15;                                 \
        if ((lane & 7) == 0) sw[row * 16 + tt] = (t0r + tt <= 499) ? s : 0.f;  \
    }                                                                          \
}

#define SYS_ITER(SV, VEXPR, I_) {                                              \
    float in0 = in_p2;                                                         \
    in_p2 = in_p1;                                                             \
    in_p1 = dpp_shr1(z_last);                                                  \
    float zpc = (SV) * a0;                                                     \
    float X = (fL * zpc + fE * zp3) + fITM * in0;                              \
    float Isyn = wA * (X * wB) + wC * in0 + wD * z_last;                       \
    float znew = izh_m(v, u, Isyn, pb, pcc, pd, (VEXPR));                      \
    if (wr) *(float2*)(ringp + (I_) * 56) = make_float2(znew, v);              \
    zp3 = zp2; zp2 = zp1; zp1 = zpc;                                           \
    z_last = znew;                                                             \
}

#define GROUP16(VF)                                                            \
    SYS_ITER(g0.x, VF(0),  0)  SYS_ITER(g0.y, VF(1),  1)                       \
    SYS_ITER(g0.z, VF(2),  2)  SYS_ITER(g0.w, VF(3),  3)                       \
    SYS_ITER(g1.x, VF(4),  4)  SYS_ITER(g1.y, VF(5),  5)                       \
    SYS_ITER(g1.z, VF(6),  6)  SYS_ITER(g1.w, VF(7),  7)                       \
    SYS_ITER(g2.x, VF(8),  8)  SYS_ITER(g2.y, VF(9),  9)                       \
    SYS_ITER(g2.z, VF(10), 10) SYS_ITER(g2.w, VF(11), 11)                      \
    SYS_ITER(g3.x, VF(12), 12) SYS_ITER(g3.y, VF(13), 13)                      \
    SYS_ITER(g3.z, VF(14), 14) SYS_ITER(g3.w, VF(15), 15)

#define VF_PRO(i)  ((i) >= offs)
#define VF_ONE(i)  true
#define VF_EPI(i)  ((i) <= 3 + offs)

// DUMP(K): runs on the LOADER during period K+1 (or post-loop for K=31).
// Ring is 64-deep; concurrent scanner writes are 16..40 iters ahead of the
// read window -> no aliasing. Slot index = iter & 63.
#define DUMP(K) {                                                              \
    const int td = lane & 15;                                                  \
    const int cc = lane >> 4;                                                  \
    const int t  = 16 * (K) - 9 + td;                                          \
    if (0 <= t && t <= 499) {                                                  \
        const float* rb = ring + cc * 14;                                      \
        float2 a2 = *(const float2*)&rb[((t)     & 63) * 56 + 0];              \
        float2 b2 = *(const float2*)&rb[((t + 3) & 63) * 56 + 2];              \
        float2 c1 = *(const float2*)&rb[((t + 6) & 63) * 56 + 4];              \
        float2 c2 = *(const float2*)&rb[((t + 6) & 63) * 56 + 6];              \
        float2 e1 = *(const float2*)&rb[((t + 9) & 63) * 56 + 8];              \
        float2 e2 = *(const float2*)&rb[((t + 9) & 63) * 56 + 10];             \
        const size_t g = (size_t)(bbase + cc) * T_ + t;                        \
        out[g]          = e1.x;   /* o_spikes  = z6  */                        \
        out[BT + g]     = e1.y;   /* v         = vM  */                        \
        out[2 * BT + g] = e2.x;   /* o_spikes2 = z62 */                        \
        out[3 * BT + g] = e2.y;   /* v2        = vM2 */                        \
        ((float4*)out)[BT + g]     = make_float4(a2.x, b2.x, c1.x, c2.x);      \
        ((float4*)out)[2 * BT + g] = make_float4(a2.y, b2.y, c1.y, c2.y);      \
    }                                                                          \
}

// Scanner period: pure scan (no dump). Ring base cycles over 4 sub-windows
// of the 64-deep ring: slot(iter j = 16K+I_) = j & 63 = (K&3)*16 + I_.
#define SCANP(K, VFSEL) {                                                      \
    const float4* sp = (const float4*)(S_lds + ((K) & 1) * 64 + c * 16);       \
    float4 g0 = sp[0], g1 = sp[1], g2 = sp[2], g3 = sp[3];                     \
    float* ringp = ring + ((K) & 3) * 896 + ringoff;                           \
    __builtin_amdgcn_s_setprio(1);                                             \
    GROUP16(VFSEL)                                                             \
    __builtin_amdgcn_s_setprio(0);                                             \
}

    // ---------------- prologue ----------------
    if (wid == 1) {
        ISSUE(0, Ae, Ao)
        REDUCE(0, Ae, Ao)      // one-time vmcnt(0) on consume
        ISSUE(1, Be, Bo)
    }
    BAR();                     // S_lds buf0 ready; ISSUE(1) stays in flight

    // ---------------- main: periods 0..31 (unrolled x2 for reg ping-pong) ---
    for (int k = 0; k < 32; k += 2) {
        if (wid == 0) {
            if (k == 0) { SCANP(k, VF_PRO) } else { SCANP(k, VF_ONE) }
        } else {
            if (k + 2 < 32) { ISSUE(k + 2, Ae, Ao) }
            if (k + 1 < 32) { REDUCE(k + 1, Be, Bo) }
            if (k >= 1) { DUMP(k - 1) }
        }
        BAR();
        if (wid == 0) {
            if (k + 1 == 31) { SCANP(k + 1, VF_EPI) } else { SCANP(k + 1, VF_ONE) }
        } else {
            if (k + 3 < 32) { ISSUE(k + 3, Be, Bo) }
            if (k + 2 < 32) { REDUCE(k + 2, Ae, Ao) }
            DUMP(k)
        }
        BAR();
    }
    // final dump (period 31's tail), after the last BAR
    if (wid == 1) { DUMP(31) }

#undef ISSUE
#undef REDUCE
#undef SYS_ITER
#undef GROUP16
#undef VF_PRO
#undef VF_ONE
#undef VF_EPI
#undef DUMP
#undef SCANP
}

extern "C" void kernel_launch(void* const* d_in, const int* in_sizes, int n_in,
                              void* d_out, int out_size, void* d_ws, size_t ws_size,
                              hipStream_t stream) {
    const float* in = (const float*)d_in[0];
    const float* w  = (const float*)d_in[1];
    float* out = (float*)d_out;

    // 512 blocks x 128 threads (1 scanner wave + 1 loader wave),
    // 4 batch rows per block; no workspace needed.
    fused_scan6_kernel<<<512, 128, 0, stream>>>(in, w, out);
}